// Round 12
// baseline (1699.546 us; speedup 1.0000x reference)
//
#include <hip/hip_runtime.h>
#include <hip/hip_fp16.h>

#define D_DIM 512

typedef __attribute__((ext_vector_type(8))) _Float16 half8;
typedef __attribute__((ext_vector_type(4))) float f32x4;
typedef __attribute__((ext_vector_type(2))) float float2v;

__device__ inline unsigned short f16b(float f) {
  return __half_as_ushort(__float2half(f));
}

// Fragment-major half-index for element (r,k) of an A-side [rows][512] matrix:
//   ((r>>4)*16 + (k>>5))*512 + ((k>>3)&3)*128 + (r&15)*8 + (k&7)
// One MFMA fragment (16 rows x 32 k) = 1KB contiguous, lane-ordered.

__device__ inline void glds16(const _Float16* g, _Float16* l) {
  __builtin_amdgcn_global_load_lds(
      (const __attribute__((address_space(1))) void*)g,
      (__attribute__((address_space(3))) void*)l, 16, 0, 0);
}

// ---------------- CSR build ----------------

__global__ __launch_bounds__(256) void k_hist(const int* __restrict__ row, int* __restrict__ cnt, int E) {
  int i = blockIdx.x * blockDim.x + threadIdx.x;
  if (i < E) atomicAdd(&cnt[row[i]], 1);
}

__global__ __launch_bounds__(1024) void k_scanA(const int* __restrict__ cnt, int* __restrict__ rp,
                                                int* __restrict__ bsum, int n) {
  __shared__ int s[1024];
  int i = blockIdx.x * 1024 + threadIdx.x;
  int v = (i < n) ? cnt[i] : 0;
  s[threadIdx.x] = v;
  __syncthreads();
  for (int off = 1; off < 1024; off <<= 1) {
    int t = (threadIdx.x >= off) ? s[threadIdx.x - off] : 0;
    __syncthreads();
    s[threadIdx.x] += t;
    __syncthreads();
  }
  if (i < n) rp[i] = s[threadIdx.x] - v;  // exclusive within block
  if (threadIdx.x == 1023) bsum[blockIdx.x] = s[1023];
}

__global__ __launch_bounds__(1024) void k_scanB(int* __restrict__ bsum, int nb) {
  __shared__ int s[1024];
  int v = (threadIdx.x < nb) ? bsum[threadIdx.x] : 0;
  s[threadIdx.x] = v;
  __syncthreads();
  for (int off = 1; off < 1024; off <<= 1) {
    int t = (threadIdx.x >= off) ? s[threadIdx.x - off] : 0;
    __syncthreads();
    s[threadIdx.x] += t;
    __syncthreads();
  }
  if (threadIdx.x < nb) bsum[threadIdx.x] = s[threadIdx.x] - v;  // exclusive
}

__global__ __launch_bounds__(256) void k_scanC(int* __restrict__ rp, const int* __restrict__ bsum, int n, int E) {
  int i = blockIdx.x * 256 + threadIdx.x;
  if (i < n) rp[i] += bsum[i >> 10];
  if (i == 0) rp[n] = E;
}

__global__ __launch_bounds__(256) void k_scatter(const int* __restrict__ row, const int* __restrict__ col,
                                                 const float* __restrict__ val, int* __restrict__ cur,
                                                 int2* __restrict__ edat, int E) {
  int i = blockIdx.x * blockDim.x + threadIdx.x;
  if (i < E) {
    int r = row[i];
    int p = atomicAdd(&cur[r], 1);
    edat[p] = make_int2(col[i], __float_as_int(val[i]));
  }
}

// ---------------- f32 X -> f16 fragment-major, with zero pad rows ----------------

__global__ __launch_bounds__(256) void k_convA(const float* __restrict__ X, unsigned* __restrict__ Xf,
                                               long nValid4, long nTot4) {
  long i = (long)blockIdx.x * 256 + threadIdx.x;  // unit: 4 elements
  long stride = (long)gridDim.x * 256;
  for (; i < nTot4; i += stride) {
    float4 x = make_float4(0.f, 0.f, 0.f, 0.f);
    if (i < nValid4) x = ((const float4*)X)[i];
    uint2 v;
    v.x = (unsigned)f16b(x.x) | ((unsigned)f16b(x.y) << 16);
    v.y = (unsigned)f16b(x.z) | ((unsigned)f16b(x.w) << 16);
    const long r = i >> 7;
    const int c0 = (int)(i & 127) * 4;
    const long halfidx = ((r >> 4) * 16 + (c0 >> 5)) * 512 + ((c0 >> 3) & 3) * 128 + (r & 15) * 8 + (c0 & 7);
    ((uint2*)Xf)[halfidx >> 2] = v;
  }
}

// ---------------- W repack: f32 [512][512] -> f16 fragment-major [k/32][n/16][g][c][8] ----------------

__global__ __launch_bounds__(256) void k_repackW(const float* __restrict__ W, _Float16* __restrict__ Wf) {
  int n = blockIdx.x * 256 + threadIdx.x;  // 0..511 (grid.x = 2)
  int kg = blockIdx.y;                      // 0..63 (8-k group)
  half8 v;
#pragma unroll
  for (int j = 0; j < 8; ++j) v[j] = (_Float16)W[(kg * 8 + j) * D_DIM + n];
  const long halfidx = ((long)(kg >> 2) * 32 + (n >> 4)) * 512 + (kg & 3) * 128 + (n & 15) * 8;
  *(half8*)(Wf + halfidx) = v;
}

// ---------------- f16 MFMA GEMM, 2-phase LDS pipeline ----------------
// 128x128 block tile, 4 waves (2x2), each wave 64x64 = 4x4 fragments of 16x16.
// A/B staged via global_load_lds(16B) into a 32KB double buffer; one barrier
// per BK=32 K-step keeps the next step's loads in flight during MFMA
// (round-11: direct-to-VGPR loads were latency-bound). Epilogue reuses the
// staging LDS for the transpose (coalesced 16B C stores).

__global__ __launch_bounds__(256) void k_gemm(const _Float16* __restrict__ A,
                                              const _Float16* __restrict__ B,
                                              _Float16* __restrict__ Cout, int MB) {
  const int id = blockIdx.x;
  const int xcd = id & 7;
  const int sgrid = id >> 3;
  const int panel = (sgrid >> 2) * 8 + xcd;
  if (panel >= MB) return;
  const int nb = sgrid & 3;

  const int tid = threadIdx.x;
  const int lane = tid & 63;
  const int w = tid >> 6;
  const int wr = w >> 1, wc = w & 1;
  const int c = lane & 15, g = lane >> 4;
  const long r0 = (long)panel * 128 + wr * 64;
  const int n0 = nb * 128 + wc * 64;

  __shared__ __align__(16) char smem[32768];  // dbuf: [buf][A 8KB | B 8KB]; reused by epilogue

  f32x4 acc[4][4] = {};

  const int f0 = w, f1 = w + 4;  // this wave's staging fragment slots
  const long aSrc0 = ((long)(panel * 8 + f0) * 16) * 512 + lane * 8;
  const long aSrc1 = ((long)(panel * 8 + f1) * 16) * 512 + lane * 8;
  const long bSrcBase = ((long)nb * 8) * 512 + lane * 8;

  // prologue: stage step 0 into buf 0
  {
    _Float16* Ad = (_Float16*)smem;
    _Float16* Bd = (_Float16*)(smem + 8192);
    glds16(A + aSrc0, Ad + f0 * 512);
    glds16(A + aSrc1, Ad + f1 * 512);
    glds16(B + bSrcBase + (long)f0 * 512, Bd + f0 * 512);
    glds16(B + bSrcBase + (long)f1 * 512, Bd + f1 * 512);
  }
  __syncthreads();

  int cur = 0;
  for (int s = 0; s < 16; ++s) {
    if (s < 15) {  // stage step s+1 into the other buffer
      const int k5 = s + 1;
      _Float16* Ad = (_Float16*)(smem + (cur ^ 1) * 16384);
      _Float16* Bd = (_Float16*)(smem + (cur ^ 1) * 16384 + 8192);
      glds16(A + aSrc0 + (long)k5 * 512, Ad + f0 * 512);
      glds16(A + aSrc1 + (long)k5 * 512, Ad + f1 * 512);
      glds16(B + bSrcBase + ((long)k5 * 32 + f0) * 512, Bd + f0 * 512);
      glds16(B + bSrcBase + ((long)k5 * 32 + f1) * 512, Bd + f1 * 512);
    }
    const _Float16* As = (const _Float16*)(smem + cur * 16384);
    const _Float16* Bs = (const _Float16*)(smem + cur * 16384 + 8192);
    half8 a[4], b[4];
#pragma unroll
    for (int mi = 0; mi < 4; ++mi) a[mi] = *(const half8*)(As + (wr * 4 + mi) * 512 + lane * 8);
#pragma unroll
    for (int ni = 0; ni < 4; ++ni) b[ni] = *(const half8*)(Bs + (wc * 4 + ni) * 512 + lane * 8);
#pragma unroll
    for (int mi = 0; mi < 4; ++mi)
#pragma unroll
      for (int ni = 0; ni < 4; ++ni)
        acc[mi][ni] = __builtin_amdgcn_mfma_f32_16x16x32_f16(a[mi], b[ni], acc[mi][ni], 0, 0, 0);
    __syncthreads();  // next-stage loads drained + all ds_reads of cur done
    cur ^= 1;
  }

  // Epilogue (smem reused): per m-slice, scatter acc (D layout: row=4g+j,
  // col=c per fragment) into this wave's LDS region, reload row-major, emit
  // two 16B f16 stores per lane.
  float (*ep)[16][68] = (float (*)[16][68])smem;
#pragma unroll
  for (int m = 0; m < 4; ++m) {
#pragma unroll
    for (int nf = 0; nf < 4; ++nf)
#pragma unroll
      for (int j = 0; j < 4; ++j)
        ep[w][g * 4 + j][nf * 16 + c] = acc[m][nf][j];
    __syncthreads();
    {
      const int row = lane >> 2;  // 0..15
      const int ch = lane & 3;    // 16-col chunk
      float v[16];
#pragma unroll
      for (int q = 0; q < 16; ++q) v[q] = ep[w][row][ch * 16 + q];
      half8 h0, h1;
#pragma unroll
      for (int q = 0; q < 8; ++q) {
        h0[q] = (_Float16)v[q];
        h1[q] = (_Float16)v[8 + q];
      }
      _Float16* dst = Cout + (r0 + m * 16 + row) * D_DIM + n0 + ch * 16;
      *(half8*)dst = h0;
      *(half8*)(dst + 8) = h1;
    }
    __syncthreads();
  }
}

// ---------------- SpMM layer-1, HALF-D (capacity experiment) ----------------
// Processes cols [d0, d0+256). Working set = 51MB half-table, testing the
// LLC-eviction hypothesis (full-D FETCH showed ~15x table re-fetch).
// 4 waves per row; edges split contiguously across waves; lane gathers 8B
// (4 f16 cols) per edge. Emits f16 H (fragment-major) for the next GEMM.

__global__ __launch_bounds__(256) void k_spmmH(const unsigned short* __restrict__ T, const int* __restrict__ rp,
                                               const int2* __restrict__ edat,
                                               unsigned short* __restrict__ Hf, int d0) {
  __shared__ float p[4][256];
  const int r = blockIdx.x;
  const int tid = threadIdx.x;
  const int w = tid >> 6, lane = tid & 63;
  const int beg = rp[r], end = rp[r + 1];
  const int cnt = end - beg;
  const int eb = beg + ((cnt * w) >> 2);
  const int ee = beg + ((cnt * (w + 1)) >> 2);

  float acc[4] = {};
  for (int e = eb; e < ee; ++e) {
    const int2 ed = edat[e];
    const float v = __int_as_float(ed.y);
    uint2 x = *(const uint2*)(T + (long)ed.x * D_DIM + d0 + lane * 4);
    float2 f0 = __half22float2(__builtin_bit_cast(__half2, x.x));
    float2 f1 = __half22float2(__builtin_bit_cast(__half2, x.y));
    acc[0] = fmaf(v, f0.x, acc[0]);
    acc[1] = fmaf(v, f0.y, acc[1]);
    acc[2] = fmaf(v, f1.x, acc[2]);
    acc[3] = fmaf(v, f1.y, acc[3]);
  }
  *(float4*)&p[w][lane * 4] = make_float4(acc[0], acc[1], acc[2], acc[3]);
  __syncthreads();

  const int cg = d0 + tid;  // this thread's global column
  float s = p[0][tid] + p[1][tid] + p[2][tid] + p[3][tid];
  s = tanhf(s);
  const long halfidx = ((long)(r >> 4) * 16 + (cg >> 5)) * 512 + ((cg >> 3) & 3) * 128 + (r & 15) * 8 + (cg & 7);
  __builtin_nontemporal_store(f16b(s), Hf + halfidx);
}

// ---------------- SpMM layer-2, full-D + l2-normalize, emit f32 ----------------

__global__ __launch_bounds__(256) void k_spmm1(const unsigned short* __restrict__ T, const int* __restrict__ rp,
                                               const int2* __restrict__ edat, float* __restrict__ out) {
  __shared__ float p[4][D_DIM];
  __shared__ float wss[4];
  const int r = blockIdx.x;
  const int tid = threadIdx.x;
  const int w = tid >> 6, lane = tid & 63;
  const int beg = rp[r], end = rp[r + 1];
  const int cnt = end - beg;
  const int eb = beg + ((cnt * w) >> 2);
  const int ee = beg + ((cnt * (w + 1)) >> 2);

  float acc[8] = {};
  const uint4* Tv = (const uint4*)T;  // 8 f16 per chunk, 64 chunks per row
  for (int e = eb; e < ee; ++e) {
    const int2 ed = edat[e];
    const float v = __int_as_float(ed.y);
    uint4 x = Tv[(long)ed.x * 64 + lane];
    unsigned xs[4] = {x.x, x.y, x.z, x.w};
#pragma unroll
    for (int q = 0; q < 4; ++q) {
      float2 f = __half22float2(__builtin_bit_cast(__half2, xs[q]));
      acc[2 * q] = fmaf(v, f.x, acc[2 * q]);
      acc[2 * q + 1] = fmaf(v, f.y, acc[2 * q + 1]);
    }
  }
  *(float4*)&p[w][lane * 8] = make_float4(acc[0], acc[1], acc[2], acc[3]);
  *(float4*)&p[w][lane * 8 + 4] = make_float4(acc[4], acc[5], acc[6], acc[7]);
  __syncthreads();

  const int c = tid * 2;  // each thread finalizes 2 columns
  float s0 = p[0][c] + p[1][c] + p[2][c] + p[3][c];
  float s1 = p[0][c + 1] + p[1][c + 1] + p[2][c + 1] + p[3][c + 1];
  s0 = tanhf(s0);
  s1 = tanhf(s1);

  float ss = fmaf(s0, s0, s1 * s1);
#pragma unroll
  for (int off = 1; off < 64; off <<= 1) ss += __shfl_xor(ss, off);
  if (lane == 0) wss[w] = ss;
  __syncthreads();
  const float tot = wss[0] + wss[1] + wss[2] + wss[3];
  const float sc = rsqrtf(fmaxf(tot, 1e-12f));
  float2v o;
  o.x = s0 * sc;
  o.y = s1 * sc;
  __builtin_nontemporal_store(o, (float2v*)out + (long)r * 256 + tid);
}

// ---------------- launch ----------------

extern "C" void kernel_launch(void* const* d_in, const int* in_sizes, int n_in,
                              void* d_out, int out_size, void* d_ws, size_t ws_size,
                              hipStream_t stream) {
  const float* X = (const float*)d_in[0];
  const int* erow = (const int*)d_in[1];
  const int* ecol = (const int*)d_in[2];
  const float* evalv = (const float*)d_in[3];
  const float* W1 = (const float*)d_in[4];
  const float* W2 = (const float*)d_in[5];
  const int N = in_sizes[0] / D_DIM;
  const int E = in_sizes[1];
  (void)n_in; (void)out_size; (void)ws_size;

  const int MB = (N + 127) / 128;     // 782 m-panels
  const long Mp = (long)MB * 128;     // padded rows: 100096

  char* wsp = (char*)d_ws;
  size_t off = 0;
  auto alloc = [&](size_t bytes) {
    void* p = wsp + off;
    off = (off + bytes + 255) & ~(size_t)255;
    return p;
  };
  unsigned short* T  = (unsigned short*)alloc(Mp * D_DIM * 2);  // GEMM output (f16 gather table, row-major)
  unsigned* Af = (unsigned*)alloc(Mp * D_DIM * 2);              // fragment-major X-f16, then H-f16
  int2* edat  = (int2*)alloc((size_t)E * 8);
  int* rowptr = (int*)alloc((size_t)(N + 1) * 4);
  int* cursor = (int*)alloc((size_t)N * 4);
  int* bsum   = (int*)alloc(1024 * 4);
  _Float16* W1f = (_Float16*)alloc((size_t)D_DIM * D_DIM * 2);
  _Float16* W2f = (_Float16*)alloc((size_t)D_DIM * D_DIM * 2);

  const int nScanBlk = (N + 1023) / 1024;
  const int gemmGrid = 32 * ((MB + 7) / 8);  // 8 xcd * 4 n-blocks * ceil(MB/8)

  // CSR build
  hipMemsetAsync(cursor, 0, (size_t)N * 4, stream);
  k_hist<<<dim3((E + 255) / 256), dim3(256), 0, stream>>>(erow, cursor, E);
  k_scanA<<<dim3(nScanBlk), dim3(1024), 0, stream>>>(cursor, rowptr, bsum, N);
  k_scanB<<<dim3(1), dim3(1024), 0, stream>>>(bsum, nScanBlk);
  k_scanC<<<dim3((N + 255) / 256), dim3(256), 0, stream>>>(rowptr, bsum, N, E);
  hipMemcpyAsync(cursor, rowptr, (size_t)N * 4, hipMemcpyDeviceToDevice, stream);
  k_scatter<<<dim3((E + 255) / 256), dim3(256), 0, stream>>>(erow, ecol, evalv, cursor, edat, E);

  // operand prep
  k_convA<<<dim3(4096), dim3(256), 0, stream>>>(X, Af, (long)N * D_DIM / 4, Mp * D_DIM / 4);
  k_repackW<<<dim3(2, 64), dim3(256), 0, stream>>>(W1, W1f);
  k_repackW<<<dim3(2, 64), dim3(256), 0, stream>>>(W2, W2f);

  // layer 1: GEMM then two half-D SpMM passes (capacity A/B experiment)
  k_gemm<<<dim3(gemmGrid), dim3(256), 0, stream>>>((const _Float16*)Af, W1f, (_Float16*)T, MB);
  k_spmmH<<<dim3(N), dim3(256), 0, stream>>>(T, rowptr, edat, (unsigned short*)Af, 0);
  k_spmmH<<<dim3(N), dim3(256), 0, stream>>>(T, rowptr, edat, (unsigned short*)Af, 256);
  // layer 2: GEMM then full-D SpMM + normalize
  k_gemm<<<dim3(gemmGrid), dim3(256), 0, stream>>>((const _Float16*)Af, W2f, (_Float16*)T, MB);
  k_spmm1<<<dim3(N), dim3(256), 0, stream>>>(T, rowptr, edat, (float*)d_out);
}

// Round 13
// 1503.789 us; speedup vs baseline: 1.1302x; 1.1302x over previous
//
#include <hip/hip_runtime.h>
#include <hip/hip_fp16.h>

#define D_DIM 512

typedef __attribute__((ext_vector_type(8))) _Float16 half8;
typedef __attribute__((ext_vector_type(4))) float f32x4;
typedef __attribute__((ext_vector_type(2))) float float2v;

__device__ inline unsigned short f16b(float f) {
  return __half_as_ushort(__float2half(f));
}

// Fragment-major half-index for element (r,k) of an A-side [rows][512] matrix:
//   ((r>>4)*16 + (k>>5))*512 + ((k>>3)&3)*128 + (r&15)*8 + (k&7)
// One MFMA fragment (16 rows x 32 k) = 1KB contiguous, lane-ordered.

__device__ inline void glds16(const _Float16* g, _Float16* l) {
  __builtin_amdgcn_global_load_lds(
      (const __attribute__((address_space(1))) void*)g,
      (__attribute__((address_space(3))) void*)l, 16, 0, 0);
}

// ---------------- CSR build ----------------

__global__ __launch_bounds__(256) void k_hist(const int* __restrict__ row, int* __restrict__ cnt, int E) {
  int i = blockIdx.x * blockDim.x + threadIdx.x;
  if (i < E) atomicAdd(&cnt[row[i]], 1);
}

__global__ __launch_bounds__(1024) void k_scanA(const int* __restrict__ cnt, int* __restrict__ rp,
                                                int* __restrict__ bsum, int n) {
  __shared__ int s[1024];
  int i = blockIdx.x * 1024 + threadIdx.x;
  int v = (i < n) ? cnt[i] : 0;
  s[threadIdx.x] = v;
  __syncthreads();
  for (int off = 1; off < 1024; off <<= 1) {
    int t = (threadIdx.x >= off) ? s[threadIdx.x - off] : 0;
    __syncthreads();
    s[threadIdx.x] += t;
    __syncthreads();
  }
  if (i < n) rp[i] = s[threadIdx.x] - v;  // exclusive within block
  if (threadIdx.x == 1023) bsum[blockIdx.x] = s[1023];
}

__global__ __launch_bounds__(1024) void k_scanB(int* __restrict__ bsum, int nb) {
  __shared__ int s[1024];
  int v = (threadIdx.x < nb) ? bsum[threadIdx.x] : 0;
  s[threadIdx.x] = v;
  __syncthreads();
  for (int off = 1; off < 1024; off <<= 1) {
    int t = (threadIdx.x >= off) ? s[threadIdx.x - off] : 0;
    __syncthreads();
    s[threadIdx.x] += t;
    __syncthreads();
  }
  if (threadIdx.x < nb) bsum[threadIdx.x] = s[threadIdx.x] - v;  // exclusive
}

__global__ __launch_bounds__(256) void k_scanC(int* __restrict__ rp, const int* __restrict__ bsum, int n, int E) {
  int i = blockIdx.x * 256 + threadIdx.x;
  if (i < n) rp[i] += bsum[i >> 10];
  if (i == 0) rp[n] = E;
}

__global__ __launch_bounds__(256) void k_scatter(const int* __restrict__ row, const int* __restrict__ col,
                                                 const float* __restrict__ val, int* __restrict__ cur,
                                                 int2* __restrict__ edat, int E) {
  int i = blockIdx.x * blockDim.x + threadIdx.x;
  if (i < E) {
    int r = row[i];
    int p = atomicAdd(&cur[r], 1);
    edat[p] = make_int2(col[i], __float_as_int(val[i]));
  }
}

// ---------------- f32 X -> f16 fragment-major, with zero pad rows ----------------

__global__ __launch_bounds__(256) void k_convA(const float* __restrict__ X, unsigned* __restrict__ Xf,
                                               long nValid4, long nTot4) {
  long i = (long)blockIdx.x * 256 + threadIdx.x;  // unit: 4 elements
  long stride = (long)gridDim.x * 256;
  for (; i < nTot4; i += stride) {
    float4 x = make_float4(0.f, 0.f, 0.f, 0.f);
    if (i < nValid4) x = ((const float4*)X)[i];
    uint2 v;
    v.x = (unsigned)f16b(x.x) | ((unsigned)f16b(x.y) << 16);
    v.y = (unsigned)f16b(x.z) | ((unsigned)f16b(x.w) << 16);
    const long r = i >> 7;
    const int c0 = (int)(i & 127) * 4;
    const long halfidx = ((r >> 4) * 16 + (c0 >> 5)) * 512 + ((c0 >> 3) & 3) * 128 + (r & 15) * 8 + (c0 & 7);
    ((uint2*)Xf)[halfidx >> 2] = v;
  }
}

// ---------------- W repack: f32 [512][512] -> f16 fragment-major [k/32][n/16][g][c][8] ----------------

__global__ __launch_bounds__(256) void k_repackW(const float* __restrict__ W, _Float16* __restrict__ Wf) {
  int n = blockIdx.x * 256 + threadIdx.x;  // 0..511 (grid.x = 2)
  int kg = blockIdx.y;                      // 0..63 (8-k group)
  half8 v;
#pragma unroll
  for (int j = 0; j < 8; ++j) v[j] = (_Float16)W[(kg * 8 + j) * D_DIM + n];
  const long halfidx = ((long)(kg >> 2) * 32 + (n >> 4)) * 512 + (kg & 3) * 128 + (n & 15) * 8;
  *(half8*)(Wf + halfidx) = v;
}

// ---------------- f16 MFMA GEMM, m97-structure (proven 874 TF on this chip) ----------------
// 128x128 tile, 4 waves (2x2), BK=64, SINGLE 32KB LDS buffer, 2 barriers per
// K-step: stage (8 glds16/wave) -> barrier(vmcnt drain) -> ds_read+32 MFMA ->
// barrier. Cross-block overlap (3-4 blocks/CU) hides the barrier drain.
// Fragment-major operands: every staged fragment = one linear 1KB wave DMA.
// Round-12 measured gemm ~240us = 11% MFMA peak @ 0.85 TB/s => latency-bound;
// this structure is the HW-verified fix.

__global__ __launch_bounds__(256) void k_gemm(const _Float16* __restrict__ A,
                                              const _Float16* __restrict__ B,
                                              _Float16* __restrict__ Cout, int MB) {
  const int id = blockIdx.x;
  const int xcd = id & 7;
  const int sgrid = id >> 3;
  const int panel = (sgrid >> 2) * 8 + xcd;
  if (panel >= MB) return;
  const int nb = sgrid & 3;

  const int tid = threadIdx.x;
  const int lane = tid & 63;
  const int w = tid >> 6;
  const int wr = w >> 1, wc = w & 1;
  const int c = lane & 15, g = lane >> 4;
  const long r0 = (long)panel * 128 + wr * 64;
  const int n0 = nb * 128 + wc * 64;

  __shared__ __align__(16) char smem[32768];  // A frags [k5loc][m] 16KB | B frags [k5loc][n] 16KB
  _Float16* Asl = (_Float16*)smem;
  _Float16* Bsl = (_Float16*)(smem + 16384);

  f32x4 acc[4][4] = {};

  const int f0 = w, f1 = w + 4;  // this wave's staging slots (m / n indices)
  const long aF0 = ((long)(panel * 8 + f0) * 16) * 512 + lane * 8;  // + k5*512
  const long aF1 = ((long)(panel * 8 + f1) * 16) * 512 + lane * 8;
  const long bBase = ((long)nb * 8) * 512 + lane * 8;               // + (k5*32 + n)*512

  for (int s = 0; s < 8; ++s) {
    const int k5a = 2 * s, k5b = 2 * s + 1;
    // stage: 8 x 1KB fragment DMAs per wave (32 frags / block)
    glds16(A + aF0 + (long)k5a * 512, Asl + (0 * 8 + f0) * 512);
    glds16(A + aF0 + (long)k5b * 512, Asl + (1 * 8 + f0) * 512);
    glds16(A + aF1 + (long)k5a * 512, Asl + (0 * 8 + f1) * 512);
    glds16(A + aF1 + (long)k5b * 512, Asl + (1 * 8 + f1) * 512);
    glds16(B + bBase + ((long)k5a * 32 + f0) * 512, Bsl + (0 * 8 + f0) * 512);
    glds16(B + bBase + ((long)k5b * 32 + f0) * 512, Bsl + (1 * 8 + f0) * 512);
    glds16(B + bBase + ((long)k5a * 32 + f1) * 512, Bsl + (0 * 8 + f1) * 512);
    glds16(B + bBase + ((long)k5b * 32 + f1) * 512, Bsl + (1 * 8 + f1) * 512);
    __syncthreads();  // drains glds (vmcnt0) + orders LDS
#pragma unroll
    for (int k5loc = 0; k5loc < 2; ++k5loc) {
      half8 a[4], b[4];
#pragma unroll
      for (int mi = 0; mi < 4; ++mi)
        a[mi] = *(const half8*)(Asl + (k5loc * 8 + wr * 4 + mi) * 512 + lane * 8);
#pragma unroll
      for (int ni = 0; ni < 4; ++ni)
        b[ni] = *(const half8*)(Bsl + (k5loc * 8 + wc * 4 + ni) * 512 + lane * 8);
#pragma unroll
      for (int mi = 0; mi < 4; ++mi)
#pragma unroll
        for (int ni = 0; ni < 4; ++ni)
          acc[mi][ni] = __builtin_amdgcn_mfma_f32_16x16x32_f16(a[mi], b[ni], acc[mi][ni], 0, 0, 0);
    }
    __syncthreads();  // all reads done before next stage overwrites
  }

  // Epilogue (smem reused): per m-slice, scatter acc (D layout: row=4g+j,
  // col=c per fragment) into this wave's LDS region, reload row-major, emit
  // two 16B f16 stores per lane.
  float (*ep)[16][68] = (float (*)[16][68])smem;
#pragma unroll
  for (int m = 0; m < 4; ++m) {
#pragma unroll
    for (int nf = 0; nf < 4; ++nf)
#pragma unroll
      for (int j = 0; j < 4; ++j)
        ep[w][g * 4 + j][nf * 16 + c] = acc[m][nf][j];
    __syncthreads();
    {
      const int row = lane >> 2;  // 0..15
      const int ch = lane & 3;    // 16-col chunk
      float v[16];
#pragma unroll
      for (int q = 0; q < 16; ++q) v[q] = ep[w][row][ch * 16 + q];
      half8 h0, h1;
#pragma unroll
      for (int q = 0; q < 8; ++q) {
        h0[q] = (_Float16)v[q];
        h1[q] = (_Float16)v[8 + q];
      }
      _Float16* dst = Cout + (r0 + m * 16 + row) * D_DIM + n0 + ch * 16;
      *(half8*)dst = h0;
      *(half8*)(dst + 8) = h1;
    }
    __syncthreads();
  }
}

// ---------------- SpMM over f16 table (row-major) + tanh ----------------
// 4 waves per row (256 threads); edges split contiguously across waves; each
// lane gathers 16B (8 f16 cols) per edge. Partials combined through 8KB LDS.
// MODE 0: emit f16 H in FRAGMENT-MAJOR layout for the next GEMM.
// MODE 1: l2-normalize, emit f32 row-major.

template <int MODE>
__global__ __launch_bounds__(256) void k_spmm(const unsigned short* __restrict__ T, const int* __restrict__ rp,
                                              const int2* __restrict__ edat,
                                              unsigned* __restrict__ Hf, float* __restrict__ out) {
  __shared__ float p[4][D_DIM];
  __shared__ float wss[4];
  const int r = blockIdx.x;
  const int tid = threadIdx.x;
  const int w = tid >> 6, lane = tid & 63;
  const int beg = rp[r], end = rp[r + 1];
  const int cnt = end - beg;
  const int eb = beg + ((cnt * w) >> 2);
  const int ee = beg + ((cnt * (w + 1)) >> 2);

  float acc[8] = {};
  const uint4* Tv = (const uint4*)T;  // 8 f16 per chunk, 64 chunks per row
  for (int e = eb; e < ee; ++e) {
    const int2 ed = edat[e];
    const float v = __int_as_float(ed.y);
    uint4 x = Tv[(long)ed.x * 64 + lane];
    unsigned xs[4] = {x.x, x.y, x.z, x.w};
#pragma unroll
    for (int q = 0; q < 4; ++q) {
      float2 f = __half22float2(__builtin_bit_cast(__half2, xs[q]));
      acc[2 * q] = fmaf(v, f.x, acc[2 * q]);
      acc[2 * q + 1] = fmaf(v, f.y, acc[2 * q + 1]);
    }
  }
  *(float4*)&p[w][lane * 8] = make_float4(acc[0], acc[1], acc[2], acc[3]);
  *(float4*)&p[w][lane * 8 + 4] = make_float4(acc[4], acc[5], acc[6], acc[7]);
  __syncthreads();

  const int c = tid * 2;  // each thread finalizes 2 columns
  float s0 = p[0][c] + p[1][c] + p[2][c] + p[3][c];
  float s1 = p[0][c + 1] + p[1][c + 1] + p[2][c + 1] + p[3][c + 1];
  s0 = tanhf(s0);
  s1 = tanhf(s1);

  if (MODE == 0) {
    // fragment-major H write: (r, c) -> halfidx, c even so one uint covers c,c+1
    unsigned hv = (unsigned)f16b(s0) | ((unsigned)f16b(s1) << 16);
    const long halfidx = ((long)(r >> 4) * 16 + (c >> 5)) * 512 + ((c >> 3) & 3) * 128 + (r & 15) * 8 + (c & 7);
    __builtin_nontemporal_store(hv, Hf + (halfidx >> 1));
  } else {
    float ss = fmaf(s0, s0, s1 * s1);
#pragma unroll
    for (int off = 1; off < 64; off <<= 1) ss += __shfl_xor(ss, off);
    if (lane == 0) wss[w] = ss;
    __syncthreads();
    const float tot = wss[0] + wss[1] + wss[2] + wss[3];
    const float sc = rsqrtf(fmaxf(tot, 1e-12f));
    float2v o;
    o.x = s0 * sc;
    o.y = s1 * sc;
    __builtin_nontemporal_store(o, (float2v*)out + (long)r * 256 + tid);
  }
}

// ---------------- launch ----------------

extern "C" void kernel_launch(void* const* d_in, const int* in_sizes, int n_in,
                              void* d_out, int out_size, void* d_ws, size_t ws_size,
                              hipStream_t stream) {
  const float* X = (const float*)d_in[0];
  const int* erow = (const int*)d_in[1];
  const int* ecol = (const int*)d_in[2];
  const float* evalv = (const float*)d_in[3];
  const float* W1 = (const float*)d_in[4];
  const float* W2 = (const float*)d_in[5];
  const int N = in_sizes[0] / D_DIM;
  const int E = in_sizes[1];
  (void)n_in; (void)out_size; (void)ws_size;

  const int MB = (N + 127) / 128;     // 782 m-panels
  const long Mp = (long)MB * 128;     // padded rows: 100096

  char* wsp = (char*)d_ws;
  size_t off = 0;
  auto alloc = [&](size_t bytes) {
    void* p = wsp + off;
    off = (off + bytes + 255) & ~(size_t)255;
    return p;
  };
  unsigned short* T  = (unsigned short*)alloc(Mp * D_DIM * 2);  // GEMM output (f16 gather table, row-major)
  unsigned* Af = (unsigned*)alloc(Mp * D_DIM * 2);              // fragment-major X-f16, then H-f16
  int2* edat  = (int2*)alloc((size_t)E * 8);
  int* rowptr = (int*)alloc((size_t)(N + 1) * 4);
  int* cursor = (int*)alloc((size_t)N * 4);
  int* bsum   = (int*)alloc(1024 * 4);
  _Float16* W1f = (_Float16*)alloc((size_t)D_DIM * D_DIM * 2);
  _Float16* W2f = (_Float16*)alloc((size_t)D_DIM * D_DIM * 2);

  const int nScanBlk = (N + 1023) / 1024;
  const int gemmGrid = 32 * ((MB + 7) / 8);  // 8 xcd * 4 n-blocks * ceil(MB/8)

  // CSR build
  hipMemsetAsync(cursor, 0, (size_t)N * 4, stream);
  k_hist<<<dim3((E + 255) / 256), dim3(256), 0, stream>>>(erow, cursor, E);
  k_scanA<<<dim3(nScanBlk), dim3(1024), 0, stream>>>(cursor, rowptr, bsum, N);
  k_scanB<<<dim3(1), dim3(1024), 0, stream>>>(bsum, nScanBlk);
  k_scanC<<<dim3((N + 255) / 256), dim3(256), 0, stream>>>(rowptr, bsum, N, E);
  hipMemcpyAsync(cursor, rowptr, (size_t)N * 4, hipMemcpyDeviceToDevice, stream);
  k_scatter<<<dim3((E + 255) / 256), dim3(256), 0, stream>>>(erow, ecol, evalv, cursor, edat, E);

  // operand prep
  k_convA<<<dim3(4096), dim3(256), 0, stream>>>(X, Af, (long)N * D_DIM / 4, Mp * D_DIM / 4);
  k_repackW<<<dim3(2, 64), dim3(256), 0, stream>>>(W1, W1f);
  k_repackW<<<dim3(2, 64), dim3(256), 0, stream>>>(W2, W2f);

  // layer 1
  k_gemm<<<dim3(gemmGrid), dim3(256), 0, stream>>>((const _Float16*)Af, W1f, (_Float16*)T, MB);
  k_spmm<0><<<dim3(N), dim3(256), 0, stream>>>(T, rowptr, edat, Af, nullptr);
  // layer 2
  k_gemm<<<dim3(gemmGrid), dim3(256), 0, stream>>>((const _Float16*)Af, W2f, (_Float16*)T, MB);
  k_spmm<1><<<dim3(N), dim3(256), 0, stream>>>(T, rowptr, edat, nullptr, (float*)d_out);
}